// Round 14
// baseline (175.548 us; speedup 1.0000x reference)
//
#include <hip/hip_runtime.h>
#include <math.h>

#define B_      4
#define C_      256
#define NTOK    4096
#define GROUPS_ 32
#define CPG_    8
#define EPS_    1e-6f
// 1/sqrt(256) * log2(e): softmax runs in exp2 domain (v_exp_f32 computes 2^x)
#define QSCALE  (0.0625f * 1.4426950408889634f)
#define NSEG    4
#define KSEG    (NTOK / NSEG)   // 1024 keys per segment
#define QB      64              // queries per flash block (4 waves x 16)

typedef __attribute__((ext_vector_type(8)))  short short8v;
typedef __attribute__((ext_vector_type(4)))  float float4v;
typedef __attribute__((ext_vector_type(4)))  unsigned short ushort4v;
typedef unsigned short ushort_t;

__device__ __forceinline__ ushort_t f2bf(float f) {
  union { float f; unsigned u; } v; v.f = f;
  unsigned r = (v.u + 0x7FFFu + ((v.u >> 16) & 1u)) >> 16;  // RNE
  return (ushort_t)r;
}
__device__ __forceinline__ float bf2f(ushort_t u) {
  union { unsigned u; float f; } v; v.u = ((unsigned)u) << 16; return v.f;
}
__device__ __forceinline__ unsigned cvtpk(float lo, float hi) {
  unsigned r;
  asm("v_cvt_pk_bf16_f32 %0, %1, %2" : "=v"(r) : "v"(lo), "v"(hi));
  return r;
}
// raw v_exp_f32: D = 2^S0, single instruction
__device__ __forceinline__ float exp2_hw(float x) {
  float r;
  asm("v_exp_f32 %0, %1" : "=v"(r) : "v"(x));
  return r;
}

__device__ __forceinline__ float4v mfma16(short8v a, short8v b, float4v c) {
  return __builtin_amdgcn_mfma_f32_16x16x32_bf16(a, b, c, 0, 0, 0);
}

// async global->LDS, 16B per lane; dest = wave-uniform base + 16*lane
__device__ __forceinline__ void gld16(const ushort_t* g, ushort_t* l) {
  __builtin_amdgcn_global_load_lds(
      (const __attribute__((address_space(1))) unsigned int*)g,
      (__attribute__((address_space(3))) unsigned int*)l, 16, 0, 0);
}

// ---------------------------------------------------------------------------
// prep: blocks 0..127  -> GN stats (mu, rstd) per (b,group)
//       blocks 128..383 -> weight f32->bf16 convert ([4][256][256])
// ---------------------------------------------------------------------------
__global__ __launch_bounds__(256) void prep(
    const float* __restrict__ x,
    const float* __restrict__ wq, const float* __restrict__ wk,
    const float* __restrict__ wv, const float* __restrict__ wo,
    float* __restrict__ stats, ushort_t* __restrict__ Wb) {
  const int t = threadIdx.x;
  if (blockIdx.x < 128) {
    const int bg = blockIdx.x;
    const size_t base = (size_t)bg * CPG_ * NTOK;
    float s = 0.f, s2 = 0.f;
    for (int i = t * 4; i < CPG_ * NTOK; i += 1024) {
      float4 v = *reinterpret_cast<const float4*>(x + base + i);
      s  += v.x + v.y + v.z + v.w;
      s2 += v.x * v.x + v.y * v.y + v.z * v.z + v.w * v.w;
    }
    #pragma unroll
    for (int m = 32; m >= 1; m >>= 1) { s += __shfl_xor(s, m); s2 += __shfl_xor(s2, m); }
    __shared__ float red[8];
    const int wv_ = t >> 6;
    if ((t & 63) == 0) { red[wv_] = s; red[4 + wv_] = s2; }
    __syncthreads();
    if (t == 0) {
      float ts  = red[0] + red[1] + red[2] + red[3];
      float ts2 = red[4] + red[5] + red[6] + red[7];
      const float inv_n = 1.0f / (float)(CPG_ * NTOK);
      float mu  = ts * inv_n;
      float var = ts2 * inv_n - mu * mu;
      stats[bg * 2]     = mu;
      stats[bg * 2 + 1] = rsqrtf(var + EPS_);
    }
  } else {
    const int id = blockIdx.x - 128;      // 0..255
    const int m = id >> 6;
    const float* srcs[4] = {wq, wk, wv, wo};
    const float* s = srcs[m];
    const int i = ((id & 63) * 256 + t) * 4;
    float4 v = *reinterpret_cast<const float4*>(s + i);
    ushort4v o4 = {f2bf(v.x), f2bf(v.y), f2bf(v.z), f2bf(v.w)};
    *reinterpret_cast<ushort4v*>(Wb + (size_t)m * 65536 + i) = o4;
  }
}

// ---------------------------------------------------------------------------
// Fused GN-apply + Q/K/V projection: stage x tile with GN applied (bf16 into
// Hs token-major), then 3 GEMMs. Q,K -> bf16 transposed [n][m] (Q prescaled
// incl. log2e); V -> key-block layout for flash15's 16x16 PV:
//   key k -> group g=(k>>2)&3, elem j=(k&3)|((k>>4)<<2); stored [c][g*8+j].
// ---------------------------------------------------------------------------
__global__ __launch_bounds__(256) void qkv_gn(
    const ushort_t* __restrict__ Wb, const float* __restrict__ bq,
    const float* __restrict__ bk, const float* __restrict__ bv,
    const float* __restrict__ x, const float* __restrict__ stats,
    const float* __restrict__ gamma, const float* __restrict__ beta,
    ushort_t* __restrict__ Qt, ushort_t* __restrict__ Kt,
    ushort_t* __restrict__ Vv) {
  const int b  = blockIdx.y;
  const int n0 = blockIdx.x * 32;
  const int t  = threadIdx.x;
  const int w  = t >> 6, l = t & 63;
  const int lg = l >> 4, ln = l & 15;
  __shared__ __align__(16) ushort_t Hs[32][264];
  const float* xb = x + (size_t)b * C_ * NTOK;
  #pragma unroll
  for (int j = 0; j < 8; ++j) {
    const int f4 = t + 256 * j;          // 0..2047
    const int c  = f4 >> 3;              // 0..255
    const int nq = (f4 & 7) * 4;         // 0..28
    float4 v = *reinterpret_cast<const float4*>(xb + (size_t)c * NTOK + n0 + nq);
    const float mu = stats[(b * GROUPS_ + (c >> 3)) * 2];
    const float rs = stats[(b * GROUPS_ + (c >> 3)) * 2 + 1];
    const float ga = gamma[c] * rs;
    const float be = beta[c] - mu * ga;
    Hs[nq + 0][c] = f2bf(v.x * ga + be);
    Hs[nq + 1][c] = f2bf(v.y * ga + be);
    Hs[nq + 2][c] = f2bf(v.z * ga + be);
    Hs[nq + 3][c] = f2bf(v.w * ga + be);
  }
  __syncthreads();

  auto gemm = [&](const ushort_t* W, float4v acc[4][2]) {
    #pragma unroll
    for (int mt = 0; mt < 4; ++mt)
      #pragma unroll
      for (int nt = 0; nt < 2; ++nt) acc[mt][nt] = (float4v){0.f, 0.f, 0.f, 0.f};
    const ushort_t* Wrow = W + (size_t)(64 * w + ln) * C_;
    #pragma unroll
    for (int kk = 0; kk < 8; ++kk) {
      short8v af[4], bfr[2];
      #pragma unroll
      for (int mt = 0; mt < 4; ++mt)
        af[mt] = *reinterpret_cast<const short8v*>(Wrow + mt * 16 * C_ + kk * 32 + 8 * lg);
      #pragma unroll
      for (int nt = 0; nt < 2; ++nt)
        bfr[nt] = *reinterpret_cast<const short8v*>(&Hs[nt * 16 + ln][kk * 32 + 8 * lg]);
      #pragma unroll
      for (int mt = 0; mt < 4; ++mt)
        #pragma unroll
        for (int nt = 0; nt < 2; ++nt)
          acc[mt][nt] = mfma16(af[mt], bfr[nt], acc[mt][nt]);
    }
  };

  float4v acc[4][2];
  // ---- Q (prescaled), K: transposed [n][m] bf16 ----
  #pragma unroll
  for (int m = 0; m < 2; ++m) {
    const float* bias = (m == 0) ? bq : bk;
    const float osc = (m == 0) ? QSCALE : 1.0f;
    ushort_t* dst = (m == 0) ? Qt : Kt;
    gemm(Wb + (size_t)m * 65536, acc);
    #pragma unroll
    for (int mt = 0; mt < 4; ++mt) {
      const int mb = 64 * w + mt * 16 + 4 * lg;
      #pragma unroll
      for (int nt = 0; nt < 2; ++nt) {
        const int n = n0 + nt * 16 + ln;
        ushort4v pk;
        #pragma unroll
        for (int r = 0; r < 4; ++r)
          pk[r] = f2bf((acc[mt][nt][r] + bias[mb + r]) * osc);
        *reinterpret_cast<ushort4v*>(dst + ((size_t)b * NTOK + n) * C_ + mb) = pk;
      }
    }
  }
  // ---- V: flash15 key-block layout ----
  gemm(Wb + 2 * 65536, acc);
  #pragma unroll
  for (int mt = 0; mt < 4; ++mt) {
    const int mb = 64 * w + mt * 16 + 4 * lg;
    #pragma unroll
    for (int nt = 0; nt < 2; ++nt) {
      const int n = n0 + nt * 16 + ln;
      const int k  = n & 31, kb = n >> 5;
      const int g  = (k >> 2) & 3;
      const int jj = (k & 3) | (((k >> 4) & 1) << 2);
      #pragma unroll
      for (int r = 0; r < 4; ++r) {
        const int c = mb + r;
        Vv[((size_t)b * (NTOK / 32) + kb) * (C_ * 32) + (size_t)c * 32 + g * 8 + jj] =
            f2bf(acc[mt][nt][r] + bv[mb + r]);
      }
    }
  }
}

// ---------------------------------------------------------------------------
// Flash attention, 16x16x32 MFMA, swapped QK^T, KV-split, XCD-clustered.
// 3 waves/SIMD design: QB=64 (4 waves x 16q), Oacc 64 AGPR, 48KB LDS
// (K dbuf 32K + V single 16K) -> 3 blocks/CU. flash9 barrier idiom.
// Per iter: entry vmcnt(0)+barrier [K(t) landed; V-buffer free];
//   issue V(t) [flight hides under QK, L2-hot via XCD-cluster] + K(t+1);
//   QK(t); softmax; mid vmcnt(4) [V(t) landed, K(t+1) in flight]+barrier;
//   PV(t).
// Fragment math (m89 layout): QK D col=lane&15=q, row=4lg+r=key-in-half;
// PV A k-bijection kappa(lg,j)=(j<4?4lg+j:16+4lg+j-4) fed directly from
// sacc registers; V global layout pre-permuted to match.
// ---------------------------------------------------------------------------
__global__ __launch_bounds__(256, 3) void flash15(
    const ushort_t* __restrict__ Qt, const ushort_t* __restrict__ Kt,
    const ushort_t* __restrict__ Vg, ushort_t* __restrict__ O0,
    ushort_t* __restrict__ Orest, float2* __restrict__ ml) {
  const int id  = blockIdx.x;
  const int xcd = id & 7, sq = id >> 3;        // sq: within-XCD sequence 0..127
  const int combo = xcd + 8 * (sq >> 6);       // 0..15, same batch per XCD
  const int b   = combo & 3;
  const int seg = combo >> 2;
  const int q0  = (sq & 63) * QB;
  const int t = threadIdx.x, w = t >> 6, l = t & 63;
  const int ln = l & 15, lg = l >> 4;

  __shared__ __align__(16) ushort_t Ks[2][32][256];   // 32 KB
  __shared__ __align__(16) ushort_t Vs[8192];         // 16 KB -> 48 KB total

  const ushort_t* Kb_ = Kt + (size_t)b * NTOK * C_;
  const ushort_t* Vb_ = Vg + (size_t)b * NTOK * C_;   // key-block layout

  // Q fragments (B operand): lane = q row q0+16w+ln, k-chunk 32kk+8lg
  short8v qf[8];
  {
    const ushort_t* qrow = Qt + ((size_t)b * NTOK + q0 + 16 * w + ln) * C_ + 8 * lg;
    #pragma unroll
    for (int kk = 0; kk < 8; ++kk)
      qf[kk] = *reinterpret_cast<const short8v*>(qrow + 32 * kk);
  }

  float4v Oacc[16];
  #pragma unroll
  for (int ct = 0; ct < 16; ++ct) Oacc[ct] = (float4v){0.f, 0.f, 0.f, 0.f};
  float m_run = -1e30f, l_run = 0.f;

  const int kbase = seg * KSEG;
  const int NT = KSEG / 32;

  // K: 16 issues (1KB = 2 rows each), 4/wave; source-XOR chunk ^= row&15
  auto STAGE_K = [&](int buf, int k0) {
    #pragma unroll
    for (int j = 0; j < 4; ++j) {
      const int i   = 4 * w + j;
      const int row = 2 * i + (l >> 5);
      const int nn  = (l & 31) ^ (row & 15);
      gld16(Kb_ + (size_t)(k0 + row) * C_ + 8 * nn, &Ks[buf][2 * i][0]);
    }
  };
  // V: contiguous 16KB tile copy, 16 issues, 4/wave
  auto STAGE_V = [&](int k0) {
    const ushort_t* vt = Vb_ + (size_t)(k0 >> 5) * (C_ * 32);
    #pragma unroll
    for (int j = 0; j < 4; ++j) {
      const int i = 4 * w + j;
      gld16(vt + i * 512 + 8 * l, &Vs[i * 512]);
    }
  };

  STAGE_K(0, kbase);

  for (int it = 0; it < NT; ++it) {
    // --- entry: K(it) landed; all waves done with PV(it-1) -> V buf free ---
    asm volatile("s_waitcnt vmcnt(0)" ::: "memory");
    __builtin_amdgcn_sched_barrier(0);
    __syncthreads();
    const bool pre = (it + 1 < NT);
    STAGE_V(kbase + 32 * it);
    if (pre) STAGE_K((it + 1) & 1, kbase + 32 * (it + 1));

    // ---- S^T = K x Q: two key-halves = two independent chains ----
    float4v s0 = (float4v){0.f, 0.f, 0.f, 0.f};
    float4v s1 = (float4v){0.f, 0.f, 0.f, 0.f};
    const ushort_t* Kc = &Ks[it & 1][0][0];
    __builtin_amdgcn_s_setprio(1);
    #pragma unroll
    for (int kk = 0; kk < 8; ++kk) {
      const int ch = 8 * ((4 * kk + lg) ^ ln);
      short8v kf0 = *reinterpret_cast<const short8v*>(Kc + ln * 256 + ch);
      short8v kf1 = *reinterpret_cast<const short8v*>(Kc + (16 + ln) * 256 + ch);
      s0 = mfma16(kf0, qf[kk], s0);
      s1 = mfma16(kf1, qf[kk], s1);
    }
    __builtin_amdgcn_s_setprio(0);

    // ---- online softmax (exp2 domain); lane owns q=ln, 8 of 32 keys ----
    float pmax = fmaxf(fmaxf(fmaxf(s0[0], s0[1]), fmaxf(s0[2], s0[3])),
                       fmaxf(fmaxf(s1[0], s1[1]), fmaxf(s1[2], s1[3])));
    pmax = fmaxf(pmax, __shfl_xor(pmax, 16));
    pmax = fmaxf(pmax, __shfl_xor(pmax, 32));
    if (!__all(pmax - m_run <= 11.0f)) {  // defer-max (T13), log2 units
      const float mnew = fmaxf(m_run, pmax);
      const float alpha = exp2_hw(m_run - mnew);
      m_run = mnew;
      l_run *= alpha;
      float av[4];
      #pragma unroll
      for (int r = 0; r < 4; ++r) av[r] = __shfl(alpha, 4 * lg + r);
      #pragma unroll
      for (int ct = 0; ct < 16; ++ct)
        #pragma unroll
        for (int r = 0; r < 4; ++r) Oacc[ct][r] *= av[r];
    }
    #pragma unroll
    for (int r = 0; r < 4; ++r) {
      s0[r] = exp2_hw(s0[r] - m_run);
      s1[r] = exp2_hw(s1[r] - m_run);
    }
    float ps = (s0[0] + s0[1]) + (s0[2] + s0[3]) +
               (s1[0] + s1[1]) + (s1[2] + s1[3]);
    ps += __shfl_xor(ps, 16);
    ps += __shfl_xor(ps, 32);
    l_run += ps;

    // ---- P -> bf16 A-frag (k-slot 8lg+j <-> key kappa(lg,j)) ----
    union { unsigned u[4]; short8v v; } P;
    P.u[0] = cvtpk(s0[0], s0[1]);
    P.u[1] = cvtpk(s0[2], s0[3]);
    P.u[2] = cvtpk(s1[0], s1[1]);
    P.u[3] = cvtpk(s1[2], s1[3]);
    const short8v pa = P.v;

    // --- mid: V(it) landed; K(it+1) stays in flight across the barrier ---
    if (pre) asm volatile("s_waitcnt vmcnt(4)" ::: "memory");
    else     asm volatile("s_waitcnt vmcnt(0)" ::: "memory");
    __builtin_amdgcn_sched_barrier(0);
    __syncthreads();

    // ---- PV: 16 c-tiles, 1 k-step each ----
    __builtin_amdgcn_s_setprio(1);
    #pragma unroll
    for (int ct = 0; ct < 16; ++ct) {
      const int c = 16 * ct + ln;
      short8v vf = *reinterpret_cast<const short8v*>(Vs + c * 32 + 8 * lg);
      Oacc[ct] = mfma16(pa, vf, Oacc[ct]);
    }
    __builtin_amdgcn_s_setprio(0);
  }

  // ---- epilogue: raw partials + (m,l) (log2 domain) ----
  ushort_t* Op = (seg == 0 ? O0 : Orest + (size_t)(seg - 1) * (size_t)B_ * NTOK * C_)
               + (size_t)b * NTOK * C_;
  #pragma unroll
  for (int ct = 0; ct < 16; ++ct)
    #pragma unroll
    for (int r = 0; r < 4; ++r) {
      const int qr = q0 + 16 * w + 4 * lg + r;
      Op[(size_t)qr * C_ + 16 * ct + ln] = f2bf(Oacc[ct][r]);
    }
  if (l < 16)
    ml[(seg * B_ + b) * NTOK + q0 + 16 * w + l] = make_float2(m_run, l_run);
}

// ---------------------------------------------------------------------------
// Final projection with fused segment-combine (m in log2 domain -> exp2_hw):
// staging combines 4 raw partials (softmax-weighted) into Hs bf16, then
// GEMM with Wo, epilogue adds bias + residual x -> f32 out.
// ---------------------------------------------------------------------------
__global__ __launch_bounds__(256) void nin_final(
    const ushort_t* __restrict__ Wo, const float* __restrict__ bo,
    const ushort_t* __restrict__ O0, const ushort_t* __restrict__ Orest,
    const float2* __restrict__ ml, const float* __restrict__ xres,
    float* __restrict__ out) {
  const int b  = blockIdx.y;
  const int n0 = blockIdx.x * 32;
  const int t  = threadIdx.x;
  const int w  = t >> 6, l = t & 63;
  const int lg = l >> 4, ln = l & 15;
  __shared__ __align__(16) ushort_t Hs[32][264];
  const size_t SLOT = (size_t)B_ * NTOK * C_;
  #pragma unroll
  for (int it = 0; it < 4; ++it) {
    const int idx = t + 256 * it;
    const int row = idx >> 5;
    const int ch  = (idx & 31) * 8;
    const int n   = n0 + row;
    float m4[NSEG], l4[NSEG], M = -1e30f;
    #pragma unroll
    for (int s = 0; s < NSEG; ++s) {
      float2 v = ml[(s * B_ + b) * NTOK + n];
      m4[s] = v.x; l4[s] = v.y;
      M = fmaxf(M, v.x);
    }
    float L = 0.f, wsc[NSEG];
    #pragma unroll
    for (int s = 0; s < NSEG; ++s) { wsc[s] = exp2_hw(m4[s] - M); L += wsc[s] * l4[s]; }
    const float inv = 1.0f / L;
    float acc8[8];
    #pragma unroll
    for (int j = 0; j < 8; ++j) acc8[j] = 0.f;
    #pragma unroll
    for (int s = 0; s < NSEG; ++s) {
      const ushort_t* op = (s == 0 ? O0 : Orest + (size_t)(s - 1) * SLOT);
      short8v v = *reinterpret_cast<const short8v*>(
          op + ((size_t)b * NTOK + n) * C_ + ch);
      #pragma unroll
      for (int j = 0; j < 8; ++j) acc8[j] += wsc[s] * bf2f((ushort_t)v[j]);
    }
    union { ushort_t us[8]; short8v v; } o8;
    #pragma unroll
    for (int j = 0; j < 8; ++j) o8.us[j] = f2bf(acc8[j] * inv);
    *reinterpret_cast<short8v*>(&Hs[row][ch]) = o8.v;
  }
  __syncthreads();

  float4v acc[4][2];
  #pragma unroll
  for (int mt = 0; mt < 4; ++mt)
    #pragma unroll
    for (int nt = 0; nt < 2; ++nt) acc[mt][nt] = (float4v){0.f, 0.f, 0.f, 0.f};
  const ushort_t* Wrow = Wo + (size_t)(64 * w + ln) * C_;
  #pragma unroll
  for (int kk = 0; kk < 8; ++kk) {
    short8v af[4], bfr[2];
    #pragma unroll
    for (int mt = 0; mt < 4; ++mt)
      af[mt] = *reinterpret_cast<const short8v*>(Wrow + mt * 16 * C_ + kk * 32 + 8 * lg);
    #pragma unroll
    for (int nt = 0; nt < 2; ++nt)
      bfr[nt] = *reinterpret_cast<const short8v*>(&Hs[nt * 16 + ln][kk * 32 + 8 * lg]);
    #pragma unroll
    for (int mt = 0; mt < 4; ++mt)
      #pragma unroll
      for (int nt = 0; nt < 2; ++nt)
        acc[mt][nt] = mfma16(af[mt], bfr[nt], acc[mt][nt]);
  }
  #pragma unroll
  for (int mt = 0; mt < 4; ++mt) {
    const int mb = 64 * w + mt * 16 + 4 * lg;
    #pragma unroll
    for (int nt = 0; nt < 2; ++nt) {
      const int n = n0 + nt * 16 + ln;
      #pragma unroll
      for (int r = 0; r < 4; ++r) {
        const size_t off = ((size_t)b * C_ + mb + r) * NTOK + n;
        out[off] = acc[mt][nt][r] + bo[mb + r] + xres[off];
      }
    }
  }
}

// ---------------------------------------------------------------------------
extern "C" void kernel_launch(void* const* d_in, const int* in_sizes, int n_in,
                              void* d_out, int out_size, void* d_ws, size_t ws_size,
                              hipStream_t stream) {
  (void)in_sizes; (void)n_in; (void)out_size; (void)ws_size;
  const float* x     = (const float*)d_in[0];
  const float* gamma = (const float*)d_in[1];
  const float* beta  = (const float*)d_in[2];
  const float* wq    = (const float*)d_in[3];
  const float* bq    = (const float*)d_in[4];
  const float* wk    = (const float*)d_in[5];
  const float* bk    = (const float*)d_in[6];
  const float* wv    = (const float*)d_in[7];
  const float* bv    = (const float*)d_in[8];
  const float* wo    = (const float*)d_in[9];
  const float* bo    = (const float*)d_in[10];
  float* out = (float*)d_out;

  ushort_t* ws16 = (ushort_t*)d_ws;
  const size_t SLOT = (size_t)B_ * NTOK * C_;  // 4,194,304 elems = 8 MB bf16

  ushort_t* Op0 = ws16;                 // slot 0: Opart seg 0
  ushort_t* Qt  = ws16 + SLOT;          // slot 1
  ushort_t* Kt  = ws16 + 2 * SLOT;      // slot 2
  ushort_t* Vb  = ws16 + 3 * SLOT;      // slot 3 (key-block layout)
  ushort_t* OpR = ws16 + 4 * SLOT;      // slots 4..6: Opart segs 1..3
  ushort_t* Wb  = ws16 + 7 * SLOT;      // [4][256][256] bf16
  float*  stats = (float*)(Wb + 4 * 65536);       // 256 f32
  float2* mlp   = (float2*)(stats + 256);         // [NSEG][B][N] (m,l)

  prep<<<dim3(384), 256, 0, stream>>>(x, wq, wk, wv, wo, stats, Wb);

  dim3 gg(NTOK / 32, B_);
  qkv_gn<<<gg, 256, 0, stream>>>(Wb, bq, bk, bv, x, stats, gamma, beta,
                                 Qt, Kt, Vb);

  flash15<<<dim3(NSEG * B_ * (NTOK / QB)), 256, 0, stream>>>(Qt, Kt, Vb, Op0, OpR, mlp);

  nin_final<<<gg, 256, 0, stream>>>(Wb + 3 * 65536, bo, Op0, OpR, mlp, x, out);
}

// Round 15
// 157.010 us; speedup vs baseline: 1.1181x; 1.1181x over previous
//
#include <hip/hip_runtime.h>
#include <math.h>

#define B_      4
#define C_      256
#define NTOK    4096
#define GROUPS_ 32
#define CPG_    8
#define EPS_    1e-6f
// 1/sqrt(256) * log2(e): softmax runs in exp2 domain (v_exp_f32 computes 2^x)
#define QSCALE  (0.0625f * 1.4426950408889634f)
#define NSEG    4
#define KSEG    (NTOK / NSEG)   // 1024 keys per segment
#define QB      128             // queries per flash block (4 waves x 32)

typedef __attribute__((ext_vector_type(8)))  short short8v;
typedef __attribute__((ext_vector_type(4)))  float float4v;
typedef __attribute__((ext_vector_type(16))) float f32x16;
typedef __attribute__((ext_vector_type(4)))  unsigned short ushort4v;
typedef unsigned short ushort_t;

__device__ __forceinline__ ushort_t f2bf(float f) {
  union { float f; unsigned u; } v; v.f = f;
  unsigned r = (v.u + 0x7FFFu + ((v.u >> 16) & 1u)) >> 16;  // RNE
  return (ushort_t)r;
}
__device__ __forceinline__ float bf2f(ushort_t u) {
  union { unsigned u; float f; } v; v.u = ((unsigned)u) << 16; return v.f;
}
__device__ __forceinline__ unsigned cvtpk(float lo, float hi) {
  unsigned r;
  asm("v_cvt_pk_bf16_f32 %0, %1, %2" : "=v"(r) : "v"(lo), "v"(hi));
  return r;
}
// raw v_exp_f32: D = 2^S0, single instruction (exp2f may route through a
// slower __ocml_exp2_f32 path -- the r12 flash regression)
__device__ __forceinline__ float exp2_hw(float x) {
  float r;
  asm("v_exp_f32 %0, %1" : "=v"(r) : "v"(x));
  return r;
}

__device__ __forceinline__ float4v mfma16(short8v a, short8v b, float4v c) {
  return __builtin_amdgcn_mfma_f32_16x16x32_bf16(a, b, c, 0, 0, 0);
}
__device__ __forceinline__ f32x16 mfma32(short8v a, short8v b, f32x16 c) {
  return __builtin_amdgcn_mfma_f32_32x32x16_bf16(a, b, c, 0, 0, 0);
}

// async global->LDS, 16B per lane; dest = wave-uniform base + 16*lane
__device__ __forceinline__ void gld16(const ushort_t* g, ushort_t* l) {
  __builtin_amdgcn_global_load_lds(
      (const __attribute__((address_space(1))) unsigned int*)g,
      (__attribute__((address_space(3))) unsigned int*)l, 16, 0, 0);
}

// ---------------------------------------------------------------------------
// prep: blocks 0..127  -> GN stats (mu, rstd) per (b,group)
//       blocks 128..383 -> weight f32->bf16 convert ([4][256][256])
// ---------------------------------------------------------------------------
__global__ __launch_bounds__(256) void prep(
    const float* __restrict__ x,
    const float* __restrict__ wq, const float* __restrict__ wk,
    const float* __restrict__ wv, const float* __restrict__ wo,
    float* __restrict__ stats, ushort_t* __restrict__ Wb) {
  const int t = threadIdx.x;
  if (blockIdx.x < 128) {
    const int bg = blockIdx.x;
    const size_t base = (size_t)bg * CPG_ * NTOK;
    float s = 0.f, s2 = 0.f;
    for (int i = t * 4; i < CPG_ * NTOK; i += 1024) {
      float4 v = *reinterpret_cast<const float4*>(x + base + i);
      s  += v.x + v.y + v.z + v.w;
      s2 += v.x * v.x + v.y * v.y + v.z * v.z + v.w * v.w;
    }
    #pragma unroll
    for (int m = 32; m >= 1; m >>= 1) { s += __shfl_xor(s, m); s2 += __shfl_xor(s2, m); }
    __shared__ float red[8];
    const int wv_ = t >> 6;
    if ((t & 63) == 0) { red[wv_] = s; red[4 + wv_] = s2; }
    __syncthreads();
    if (t == 0) {
      float ts  = red[0] + red[1] + red[2] + red[3];
      float ts2 = red[4] + red[5] + red[6] + red[7];
      const float inv_n = 1.0f / (float)(CPG_ * NTOK);
      float mu  = ts * inv_n;
      float var = ts2 * inv_n - mu * mu;
      stats[bg * 2]     = mu;
      stats[bg * 2 + 1] = rsqrtf(var + EPS_);
    }
  } else {
    const int id = blockIdx.x - 128;      // 0..255
    const int m = id >> 6;
    const float* srcs[4] = {wq, wk, wv, wo};
    const float* s = srcs[m];
    const int i = ((id & 63) * 256 + t) * 4;
    float4 v = *reinterpret_cast<const float4*>(s + i);
    ushort4v o4 = {f2bf(v.x), f2bf(v.y), f2bf(v.z), f2bf(v.w)};
    *reinterpret_cast<ushort4v*>(Wb + (size_t)m * 65536 + i) = o4;
  }
}

// ---------------------------------------------------------------------------
// Fused GN-apply + Q/K/V projection: stage x tile with GN applied (bf16 into
// Hs token-major), then 3 GEMMs. Q,K -> bf16 transposed [n][m] (Q prescaled
// incl. log2e); V -> key-block swizzled layout.
// ---------------------------------------------------------------------------
__global__ __launch_bounds__(256) void qkv_gn(
    const ushort_t* __restrict__ Wb, const float* __restrict__ bq,
    const float* __restrict__ bk, const float* __restrict__ bv,
    const float* __restrict__ x, const float* __restrict__ stats,
    const float* __restrict__ gamma, const float* __restrict__ beta,
    ushort_t* __restrict__ Qt, ushort_t* __restrict__ Kt,
    ushort_t* __restrict__ Vv) {
  const int b  = blockIdx.y;
  const int n0 = blockIdx.x * 32;
  const int t  = threadIdx.x;
  const int w  = t >> 6, l = t & 63;
  const int lg = l >> 4, ln = l & 15;
  __shared__ __align__(16) ushort_t Hs[32][264];
  const float* xb = x + (size_t)b * C_ * NTOK;
  #pragma unroll
  for (int j = 0; j < 8; ++j) {
    const int f4 = t + 256 * j;          // 0..2047
    const int c  = f4 >> 3;              // 0..255
    const int nq = (f4 & 7) * 4;         // 0..28
    float4 v = *reinterpret_cast<const float4*>(xb + (size_t)c * NTOK + n0 + nq);
    const float mu = stats[(b * GROUPS_ + (c >> 3)) * 2];
    const float rs = stats[(b * GROUPS_ + (c >> 3)) * 2 + 1];
    const float ga = gamma[c] * rs;
    const float be = beta[c] - mu * ga;
    Hs[nq + 0][c] = f2bf(v.x * ga + be);
    Hs[nq + 1][c] = f2bf(v.y * ga + be);
    Hs[nq + 2][c] = f2bf(v.z * ga + be);
    Hs[nq + 3][c] = f2bf(v.w * ga + be);
  }
  __syncthreads();

  auto gemm = [&](const ushort_t* W, float4v acc[4][2]) {
    #pragma unroll
    for (int mt = 0; mt < 4; ++mt)
      #pragma unroll
      for (int nt = 0; nt < 2; ++nt) acc[mt][nt] = (float4v){0.f, 0.f, 0.f, 0.f};
    const ushort_t* Wrow = W + (size_t)(64 * w + ln) * C_;
    #pragma unroll
    for (int kk = 0; kk < 8; ++kk) {
      short8v af[4], bfr[2];
      #pragma unroll
      for (int mt = 0; mt < 4; ++mt)
        af[mt] = *reinterpret_cast<const short8v*>(Wrow + mt * 16 * C_ + kk * 32 + 8 * lg);
      #pragma unroll
      for (int nt = 0; nt < 2; ++nt)
        bfr[nt] = *reinterpret_cast<const short8v*>(&Hs[nt * 16 + ln][kk * 32 + 8 * lg]);
      #pragma unroll
      for (int mt = 0; mt < 4; ++mt)
        #pragma unroll
        for (int nt = 0; nt < 2; ++nt)
          acc[mt][nt] = mfma16(af[mt], bfr[nt], acc[mt][nt]);
    }
  };

  float4v acc[4][2];
  // ---- Q (prescaled), K: transposed [n][m] bf16 ----
  #pragma unroll
  for (int m = 0; m < 2; ++m) {
    const float* bias = (m == 0) ? bq : bk;
    const float osc = (m == 0) ? QSCALE : 1.0f;
    ushort_t* dst = (m == 0) ? Qt : Kt;
    gemm(Wb + (size_t)m * 65536, acc);
    #pragma unroll
    for (int mt = 0; mt < 4; ++mt) {
      const int mb = 64 * w + mt * 16 + 4 * lg;
      #pragma unroll
      for (int nt = 0; nt < 2; ++nt) {
        const int n = n0 + nt * 16 + ln;
        ushort4v pk;
        #pragma unroll
        for (int r = 0; r < 4; ++r)
          pk[r] = f2bf((acc[mt][nt][r] + bias[mb + r]) * osc);
        *reinterpret_cast<ushort4v*>(dst + ((size_t)b * NTOK + n) * C_ + mb) = pk;
      }
    }
  }
  // ---- V: key-block layout [n/32][c][slot][e], slot = o ^ ((c>>1)&3) ----
  gemm(Wb + 2 * 65536, acc);
  #pragma unroll
  for (int mt = 0; mt < 4; ++mt) {
    const int mb = 64 * w + mt * 16 + 4 * lg;
    #pragma unroll
    for (int nt = 0; nt < 2; ++nt) {
      const int n = n0 + nt * 16 + ln;
      const int k  = n & 31, kb = n >> 5;
      const int e  = (k & 3) | (((k >> 3) & 1) << 2);
      const int o  = ((k >> 2) & 1) | (((k >> 4) & 1) << 1);
      #pragma unroll
      for (int r = 0; r < 4; ++r) {
        const int c = mb + r;
        const int s = o ^ ((c >> 1) & 3);
        Vv[((size_t)b * (NTOK / 32) + kb) * (C_ * 32) + (size_t)c * 32 + s * 8 + e] =
            f2bf(acc[mt][nt][r] + bv[mb + r]);
      }
    }
  }
}

// ---------------------------------------------------------------------------
// Flash attention, 32x32x16 MFMA, swapped QK^T, KV-split, XCD-clustered.
// PROVEN flash9 structure (r9, 106us): 2 barriers (__syncthreads), counted
// vmcnt, K/V double-buffered, no carried state. Softmax in exp2 domain via
// raw v_exp_f32 (exp2_hw).
// ---------------------------------------------------------------------------
__global__ __launch_bounds__(256, 2) void flash14(
    const ushort_t* __restrict__ Qt, const ushort_t* __restrict__ Kt,
    const ushort_t* __restrict__ Vg, ushort_t* __restrict__ O0,
    ushort_t* __restrict__ Orest, float2* __restrict__ ml) {
  const int id  = blockIdx.x;
  const int xcd = id & 7, sq = id >> 3;        // sq: within-XCD sequence 0..63
  const int combo = xcd + 8 * (sq >> 5);       // 0..15, same batch per XCD
  const int b   = combo & 3;
  const int seg = combo >> 2;
  const int q0  = (sq & 31) * QB;
  const int t = threadIdx.x, w = t >> 6, l = t & 63;
  const int ln = l & 31, hi = l >> 5;

  __shared__ __align__(16) ushort_t Ks[2][32][256];   // 32 KB
  __shared__ __align__(16) ushort_t Vs[2][8192];      // 32 KB (16KB per buf)

  const ushort_t* Kb_ = Kt + (size_t)b * NTOK * C_;
  const ushort_t* Vb_ = Vg + (size_t)b * NTOK * C_;   // key-block layout

  // Q fragments (B operand), resident: lane = q row q0+32w+ln
  short8v qf[16];
  {
    const ushort_t* qrow = Qt + ((size_t)b * NTOK + q0 + 32 * w + ln) * C_ + 8 * hi;
    #pragma unroll
    for (int kk = 0; kk < 16; ++kk)
      qf[kk] = *reinterpret_cast<const short8v*>(qrow + 16 * kk);
  }

  f32x16 Oacc[8];
  #pragma unroll
  for (int ct = 0; ct < 8; ++ct)
    #pragma unroll
    for (int r = 0; r < 16; ++r) Oacc[ct][r] = 0.f;
  float m_run = -1e30f, l_run = 0.f;

  const int kbase = seg * KSEG;
  const int NT = KSEG / 32;

  // every wave: 4 K issues then 4 V issues (order matters for vmcnt counts)
  auto STAGE_K = [&](int buf, int k0) {
    #pragma unroll
    for (int j = 0; j < 4; ++j) {
      const int i   = 4 * w + j;             // K issue 0..15 (1KB each)
      const int row = 2 * i + (l >> 5);      // key row 0..31
      const int nn  = (l & 31) ^ (row & 15); // bank-spread source chunk
      gld16(Kb_ + (size_t)(k0 + row) * C_ + 8 * nn, &Ks[buf][2 * i][0]);
    }
  };
  auto STAGE_V = [&](int buf, int k0) {
    const ushort_t* vt = Vb_ + (size_t)(k0 >> 5) * (C_ * 32);
    #pragma unroll
    for (int j = 0; j < 4; ++j) {
      const int i = 4 * w + j;               // V issue 0..15 (1KB each)
      gld16(vt + i * 512 + 8 * l, &Vs[buf][i * 512]);
    }
  };

  int cur = 0;
  STAGE_K(0, kbase);
  STAGE_V(0, kbase);

  for (int it = 0; it < NT; ++it) {
    // --- entry: K(it) landed; V(it) may still fly ---
    asm volatile("s_waitcnt vmcnt(4)" ::: "memory");
    __builtin_amdgcn_sched_barrier(0);
    __syncthreads();
    const bool pre = (it + 1 < NT);
    if (pre) {
      const int nxt = kbase + 32 * (it + 1);
      STAGE_K(cur ^ 1, nxt);
      STAGE_V(cur ^ 1, nxt);
    }

    // ---- S^T = K x Q, two independent MFMA chains ----
    f32x16 sA, sB;
    #pragma unroll
    for (int r = 0; r < 16; ++r) { sA[r] = 0.f; sB[r] = 0.f; }
    const ushort_t* Kc = &Ks[cur][0][0];
    __builtin_amdgcn_s_setprio(1);
    #pragma unroll
    for (int kk = 0; kk < 16; kk += 2) {
      short8v k0f = *reinterpret_cast<const short8v*>(
          Kc + ln * 256 + 8 * ((2 * kk + hi) ^ (ln & 15)));
      short8v k1f = *reinterpret_cast<const short8v*>(
          Kc + ln * 256 + 8 * ((2 * kk + 2 + hi) ^ (ln & 15)));
      sA = mfma32(k0f, qf[kk], sA);
      sB = mfma32(k1f, qf[kk + 1], sB);
    }
    __builtin_amdgcn_s_setprio(0);
    f32x16 sacc = sA + sB;

    // ---- online softmax in exp2 domain (balanced trees); lane owns q=ln ---
    float mx8[8];
    #pragma unroll
    for (int j = 0; j < 8; ++j) mx8[j] = fmaxf(sacc[j], sacc[j + 8]);
    #pragma unroll
    for (int j = 0; j < 4; ++j) mx8[j] = fmaxf(mx8[j], mx8[j + 4]);
    float pmax = fmaxf(fmaxf(mx8[0], mx8[2]), fmaxf(mx8[1], mx8[3]));
    pmax = fmaxf(pmax, __shfl_xor(pmax, 32));
    if (!__all(pmax - m_run <= 11.0f)) {  // defer-max (T13), log2 units
      const float mnew = fmaxf(m_run, pmax);
      const float alpha = exp2_hw(m_run - mnew);
      m_run = mnew;
      l_run *= alpha;
      float av[16];
      #pragma unroll
      for (int r = 0; r < 16; ++r)
        av[r] = __shfl(alpha, (r & 3) + 8 * (r >> 2) + 4 * hi);
      #pragma unroll
      for (int ct = 0; ct < 8; ++ct)
        #pragma unroll
        for (int r = 0; r < 16; ++r) Oacc[ct][r] *= av[r];
    }
    float sm8[8];
    #pragma unroll
    for (int r = 0; r < 16; ++r) sacc[r] = exp2_hw(sacc[r] - m_run);
    #pragma unroll
    for (int j = 0; j < 8; ++j) sm8[j] = sacc[j] + sacc[j + 8];
    #pragma unroll
    for (int j = 0; j < 4; ++j) sm8[j] += sm8[j + 4];
    float ps = (sm8[0] + sm8[2]) + (sm8[1] + sm8[3]);
    ps += __shfl_xor(ps, 32);
    l_run += ps;

    // ---- P -> bf16 A-frags (T12 cvt_pk; union dies before the barrier) ----
    union { unsigned u[4]; short8v v; } P0, P1;
    #pragma unroll
    for (int j = 0; j < 4; ++j) {
      P0.u[j] = cvtpk(sacc[2 * j], sacc[2 * j + 1]);
      P1.u[j] = cvtpk(sacc[8 + 2 * j], sacc[9 + 2 * j]);
    }
    const short8v pa0 = P0.v, pa1 = P1.v;

    // --- mid: V(it) landed; K/V(it+1) stay in flight across the barrier ---
    if (pre) asm volatile("s_waitcnt vmcnt(8)" ::: "memory");
    else     asm volatile("s_waitcnt vmcnt(0)" ::: "memory");
    __builtin_amdgcn_sched_barrier(0);
    __syncthreads();

    // ---- PV ----
    const ushort_t* Vc = &Vs[cur][0];
    const int sx = (ln >> 1) & 3;
    __builtin_amdgcn_s_setprio(1);
    #pragma unroll
    for (int ct = 0; ct < 8; ++ct) {
      const int c = 32 * ct + ln;
      const ushort_t* vr = Vc + c * 32;
      short8v v0 = *reinterpret_cast<const short8v*>(vr + 8 * (hi ^ sx));
      short8v v1 = *reinterpret_cast<const short8v*>(vr + 8 * ((2 | hi) ^ sx));
      Oacc[ct] = mfma32(pa0, v0, Oacc[ct]);
      Oacc[ct] = mfma32(pa1, v1, Oacc[ct]);
    }
    __builtin_amdgcn_s_setprio(0);
    cur ^= 1;
  }

  // ---- epilogue: raw partials + (m,l) (log2 domain) ----
  ushort_t* Op = (seg == 0 ? O0 : Orest + (size_t)(seg - 1) * (size_t)B_ * NTOK * C_)
               + (size_t)b * NTOK * C_;
  #pragma unroll
  for (int ct = 0; ct < 8; ++ct)
    #pragma unroll
    for (int r = 0; r < 16; ++r) {
      const int qr = q0 + 32 * w + (r & 3) + 8 * (r >> 2) + 4 * hi;
      Op[(size_t)qr * C_ + 32 * ct + ln] = f2bf(Oacc[ct][r]);
    }
  if (hi == 0)
    ml[(seg * B_ + b) * NTOK + q0 + 32 * w + ln] = make_float2(m_run, l_run);
}

// ---------------------------------------------------------------------------
// Final projection with fused segment-combine (m in log2 domain -> exp2_hw):
// staging combines 4 raw partials (softmax-weighted) into Hs bf16, then
// GEMM with Wo, epilogue adds bias + residual x -> f32 out.
// ---------------------------------------------------------------------------
__global__ __launch_bounds__(256) void nin_final(
    const ushort_t* __restrict__ Wo, const float* __restrict__ bo,
    const ushort_t* __restrict__ O0, const ushort_t* __restrict__ Orest,
    const float2* __restrict__ ml, const float* __restrict__ xres,
    float* __restrict__ out) {
  const int b  = blockIdx.y;
  const int n0 = blockIdx.x * 32;
  const int t  = threadIdx.x;
  const int w  = t >> 6, l = t & 63;
  const int lg = l >> 4, ln = l & 15;
  __shared__ __align__(16) ushort_t Hs[32][264];
  const size_t SLOT = (size_t)B_ * NTOK * C_;
  #pragma unroll
  for (int it = 0; it < 4; ++it) {
    const int idx = t + 256 * it;
    const int row = idx >> 5;
    const int ch  = (idx & 31) * 8;
    const int n   = n0 + row;
    float m4[NSEG], l4[NSEG], M = -1e30f;
    #pragma unroll
    for (int s = 0; s < NSEG; ++s) {
      float2 v = ml[(s * B_ + b) * NTOK + n];
      m4[s] = v.x; l4[s] = v.y;
      M = fmaxf(M, v.x);
    }
    float L = 0.f, wsc[NSEG];
    #pragma unroll
    for (int s = 0; s < NSEG; ++s) { wsc[s] = exp2_hw(m4[s] - M); L += wsc[s] * l4[s]; }
    const float inv = 1.0f / L;
    float acc8[8];
    #pragma unroll
    for (int j = 0; j < 8; ++j) acc8[j] = 0.f;
    #pragma unroll
    for (int s = 0; s < NSEG; ++s) {
      const ushort_t* op = (s == 0 ? O0 : Orest + (size_t)(s - 1) * SLOT);
      short8v v = *reinterpret_cast<const short8v*>(
          op + ((size_t)b * NTOK + n) * C_ + ch);
      #pragma unroll
      for (int j = 0; j < 8; ++j) acc8[j] += wsc[s] * bf2f((ushort_t)v[j]);
    }
    union { ushort_t us[8]; short8v v; } o8;
    #pragma unroll
    for (int j = 0; j < 8; ++j) o8.us[j] = f2bf(acc8[j] * inv);
    *reinterpret_cast<short8v*>(&Hs[row][ch]) = o8.v;
  }
  __syncthreads();

  float4v acc[4][2];
  #pragma unroll
  for (int mt = 0; mt < 4; ++mt)
    #pragma unroll
    for (int nt = 0; nt < 2; ++nt) acc[mt][nt] = (float4v){0.f, 0.f, 0.f, 0.f};
  const ushort_t* Wrow = Wo + (size_t)(64 * w + ln) * C_;
  #pragma unroll
  for (int kk = 0; kk < 8; ++kk) {
    short8v af[4], bfr[2];
    #pragma unroll
    for (int mt = 0; mt < 4; ++mt)
      af[mt] = *reinterpret_cast<const short8v*>(Wrow + mt * 16 * C_ + kk * 32 + 8 * lg);
    #pragma unroll
    for (int nt = 0; nt < 2; ++nt)
      bfr[nt] = *reinterpret_cast<const short8v*>(&Hs[nt * 16 + ln][kk * 32 + 8 * lg]);
    #pragma unroll
    for (int mt = 0; mt < 4; ++mt)
      #pragma unroll
      for (int nt = 0; nt < 2; ++nt)
        acc[mt][nt] = mfma16(af[mt], bfr[nt], acc[mt][nt]);
  }
  #pragma unroll
  for (int mt = 0; mt < 4; ++mt) {
    const int mb = 64 * w + mt * 16 + 4 * lg;
    #pragma unroll
    for (int nt = 0; nt < 2; ++nt) {
      const int n = n0 + nt * 16 + ln;
      #pragma unroll
      for (int r = 0; r < 4; ++r) {
        const size_t off = ((size_t)b * C_ + mb + r) * NTOK + n;
        out[off] = acc[mt][nt][r] + bo[mb + r] + xres[off];
      }
    }
  }
}

// ---------------------------------------------------------------------------
extern "C" void kernel_launch(void* const* d_in, const int* in_sizes, int n_in,
                              void* d_out, int out_size, void* d_ws, size_t ws_size,
                              hipStream_t stream) {
  (void)in_sizes; (void)n_in; (void)out_size; (void)ws_size;
  const float* x     = (const float*)d_in[0];
  const float* gamma = (const float*)d_in[1];
  const float* beta  = (const float*)d_in[2];
  const float* wq    = (const float*)d_in[3];
  const float* bq    = (const float*)d_in[4];
  const float* wk    = (const float*)d_in[5];
  const float* bk    = (const float*)d_in[6];
  const float* wv    = (const float*)d_in[7];
  const float* bv    = (const float*)d_in[8];
  const float* wo    = (const float*)d_in[9];
  const float* bo    = (const float*)d_in[10];
  float* out = (float*)d_out;

  ushort_t* ws16 = (ushort_t*)d_ws;
  const size_t SLOT = (size_t)B_ * NTOK * C_;  // 4,194,304 elems = 8 MB bf16

  ushort_t* Op0 = ws16;                 // slot 0: Opart seg 0
  ushort_t* Qt  = ws16 + SLOT;          // slot 1
  ushort_t* Kt  = ws16 + 2 * SLOT;      // slot 2
  ushort_t* Vb  = ws16 + 3 * SLOT;      // slot 3 (key-block layout)
  ushort_t* OpR = ws16 + 4 * SLOT;      // slots 4..6: Opart segs 1..3
  ushort_t* Wb  = ws16 + 7 * SLOT;      // [4][256][256] bf16
  float*  stats = (float*)(Wb + 4 * 65536);       // 256 f32
  float2* mlp   = (float2*)(stats + 256);         // [NSEG][B][N] (m,l)

  prep<<<dim3(384), 256, 0, stream>>>(x, wq, wk, wv, wo, stats, Wb);

  dim3 gg(NTOK / 32, B_);
  qkv_gn<<<gg, 256, 0, stream>>>(Wb, bq, bk, bv, x, stats, gamma, beta,
                                 Qt, Kt, Vb);

  flash14<<<dim3(NSEG * B_ * (NTOK / QB)), 256, 0, stream>>>(Qt, Kt, Vb, Op0, OpR, mlp);

  nin_final<<<gg, 256, 0, stream>>>(Wb + 3 * 65536, bo, Op0, OpR, mlp, x, out);
}